// Round 1
// baseline (855.987 us; speedup 1.0000x reference)
//
#include <hip/hip_runtime.h>

// Problem constants (MultiHeadAttention_79431125172249)
// All float tensors are fp32 (reference dtype); mask is int32; output fp32.
#define B_  32
#define S_  4096
#define E_  1024
#define H_  16
#define D_  64
#define NV_ 64
#define HD_ 1024   // H_*D_

typedef unsigned short ushort_t;
typedef __attribute__((ext_vector_type(8))) short  short8;   // 8 x bf16 (4 VGPRs)
typedef __attribute__((ext_vector_type(4))) float  floatx4;  // MFMA f32 acc

__device__ __forceinline__ ushort_t f2b(float f) {  // fp32 -> bf16 RNE
  union { float f; unsigned int u; } v; v.f = f;
  return (ushort_t)((v.u + 0x7FFFu + ((v.u >> 16) & 1u)) >> 16);
}
// pack two fp32 -> two bf16 (round-half-up; bias-free enough for 2% tol)
__device__ __forceinline__ unsigned int pk2(float lo, float hi) {
  union { float f; unsigned int u; } a, b; a.f = lo; b.f = hi;
  return ((a.u + 0x8000u) >> 16) | ((b.u + 0x8000u) & 0xFFFF0000u);
}

// Workgroup barrier that drains LDS ops ONLY. Unlike __syncthreads (which the
// compiler lowers to s_waitcnt vmcnt(0) lgkmcnt(0); s_barrier), this leaves
// prefetched global loads in flight across the barrier (counted-vmcnt idiom).
__device__ __forceinline__ void bar_lds() {
  asm volatile("s_waitcnt lgkmcnt(0)" ::: "memory");
  __builtin_amdgcn_s_barrier();
  asm volatile("" ::: "memory");
}

// ---------------------------------------------------------------------------
// Kernel A: q[b,h,:] = seq1[b]@Wq_h + bq_h  then  r[b,h,:] = (Wk_h @ q)/sqrt(D)
// r stored bf16 in workspace, layout [b][h][e]. bk skipped (softmax-invariant).
// ---------------------------------------------------------------------------
__global__ __launch_bounds__(256) void qr_kernel(
    const float* __restrict__ seq1, const float* __restrict__ Wq,
    const float* __restrict__ bq,   const float* __restrict__ Wk,
    ushort_t* __restrict__ r_bf) {
  __shared__ __align__(16) float qp[4][64];
  __shared__ __align__(16) float qv[64];
  const int b = blockIdx.x / H_, h = blockIdx.x % H_;
  const int t = threadIdx.x;
  const int d = t & 63, quarter = t >> 6;

  // stage 1: q_d = sum_e seq1[b,e] * Wq[e, h*64+d]; K=1024 split in 4 chunks
  {
    const float* s1 = seq1 + (size_t)b * E_;
    const float* wq = Wq + h * D_ + d;
    float sum = 0.f;
    const int e0 = quarter * 256;
#pragma unroll 8
    for (int e = e0; e < e0 + 256; ++e)
      sum += s1[e] * wq[(size_t)e * HD_];
    qp[quarter][d] = sum;
  }
  __syncthreads();
  if (t < 64) qv[t] = qp[0][t] + qp[1][t] + qp[2][t] + qp[3][t] + bq[h * D_ + t];
  __syncthreads();

  // stage 2: r_e = (1/8) * sum_d Wk[e, h*64+d] * q_d   (4 e's per thread)
  for (int i = 0; i < 4; ++i) {
    const int e = t + 256 * i;
    const float* wk = Wk + (size_t)e * HD_ + h * D_;
    float rs = 0.f;
#pragma unroll
    for (int g = 0; g < 16; ++g) {
      const float4 w4 = *(const float4*)(wk + g * 4);
      rs += w4.x * qv[g * 4 + 0] + w4.y * qv[g * 4 + 1] +
            w4.z * qv[g * 4 + 2] + w4.w * qv[g * 4 + 3];
    }
    r_bf[((size_t)b * H_ + h) * E_ + e] = f2b(rs * 0.125f);  // fold 1/sqrt(64)
  }
}

// ---------------------------------------------------------------------------
// Kernel B: flash pass over seq2. One block = (batch b, S-chunk), all 16 heads.
// Restructured vs. previous version:
//   - r B-fragments live in registers (read once); freed 33 KB LDS becomes the
//     second X buffer -> double-buffered staging at unchanged LDS footprint.
//   - tile i+1 global loads issued at top of iter i, written to the alternate
//     buffer after softmax; raw s_barrier + lgkm-only drains keep them in
//     flight (no vmcnt(0) at barriers).
//   - softmax computed redundantly by all 4 waves with m/l in registers;
//     barriers cut 4 -> 2 per tile.
// ---------------------------------------------------------------------------
__global__ __launch_bounds__(256, 2) void attn_kernel(
    const float* __restrict__ seq2, const int* __restrict__ mask,
    const ushort_t* __restrict__ r_bf, float* __restrict__ cpart,
    float* __restrict__ mlpart, int NC, int TPC) {
  __shared__ __align__(16) ushort_t xbuf[2][16][1032];  // X dbuf (buf1 stages r first)
  __shared__ __align__(16) float scp[4][16][17];        // per-wave score partials
  __shared__ __align__(16) float Pt[16][16];            // p[s][h]
  __shared__ __align__(16) float alphaS[16];

  const int b = blockIdx.y, chunk = blockIdx.x;
  const int t = threadIdx.x;
  const int lane = t & 63, w = t >> 6;
  const int s0 = chunk * (TPC * 16);
  const int e0 = t * 4;                  // this thread's 4 e-columns
  const int m = lane & 15, q = lane >> 4;

  const float4* xsrc = (const float4*)(seq2 + ((size_t)b * S_ + s0) * E_);
  const int* mbase = mask + (size_t)b * S_ + s0 + q * 4;

  // --- prologue ---
  // r loads FIRST (oldest in vmcnt queue: their LDS-write wait won't drain the
  // tile-0 x-loads issued after them).
  uint4 rstage[8];
  {
    const uint4* src = (const uint4*)(r_bf + (size_t)b * H_ * E_);
#pragma unroll
    for (int i = 0; i < 8; ++i) rstage[i] = src[t + 256 * i];
  }
  // mask for tile 0 before x-loads (so its use never forces an x-load drain)
  int4 mk = *(const int4*)(mbase);
  float4 v[16];
#pragma unroll
  for (int i = 0; i < 16; ++i) v[i] = xsrc[t + 256 * i];

  // stage r (bf16 [h][e]) into xbuf[1]
#pragma unroll
  for (int i = 0; i < 8; ++i) {
    const int f = t + 256 * i;
    *(uint4*)&xbuf[1][f >> 7][(f & 127) * 8] = rstage[i];
  }
  bar_lds();
  // pull this wave's B-fragments (its K-quarter) to registers, once
  short8 rf[8];
#pragma unroll
  for (int kk = 0; kk < 8; ++kk)
    rf[kk] = *(const short8*)&xbuf[1][m][w * 256 + kk * 32 + q * 8];
  bar_lds();  // all waves done reading xbuf[1]; it may now be overwritten

  // stage tile 0 into xbuf[0] (waits the v-loads here, at use)
#pragma unroll
  for (int i = 0; i < 16; ++i)
    *(uint2*)&xbuf[0][i][e0] =
        make_uint2(pk2(v[i].x, v[i].y), pk2(v[i].z, v[i].w));
  bar_lds();  // xbuf[0] ready

  float c[16][4];
#pragma unroll
  for (int h = 0; h < 16; ++h)
#pragma unroll
    for (int j = 0; j < 4; ++j) c[h][j] = 0.f;
  float m_reg = -3e38f, l_reg = 0.f;   // per-lane running max/sum for h = m

  for (int it = 0; it < TPC; ++it) {
    const int cur = it & 1, nxt = cur ^ 1;
    const bool pf = (it + 1 < TPC);
    int4 mk_n;
    // A) issue next tile's loads; they stay in flight across both barriers
    if (pf) {
      mk_n = *(const int4*)(mbase + (it + 1) * 16);
#pragma unroll
      for (int i = 0; i < 16; ++i)
        v[i] = xsrc[(it + 1) * 4096 + t + 256 * i];
    }
    // B) partial scores: wave w covers e in [w*256, w*256+256) -> 8 k-steps
    {
      floatx4 acc = {0.f, 0.f, 0.f, 0.f};
      __builtin_amdgcn_s_setprio(1);
#pragma unroll
      for (int kk = 0; kk < 8; ++kk) {
        short8 av = *(const short8*)&xbuf[cur][m][w * 256 + kk * 32 + q * 8];
        acc = __builtin_amdgcn_mfma_f32_16x16x32_bf16(av, rf[kk], acc, 0, 0, 0);
      }
      __builtin_amdgcn_s_setprio(0);
      // C: col=lane&15 (=h), row=q*4+j (=s)
#pragma unroll
      for (int j = 0; j < 4; ++j) scp[w][q * 4 + j][m] = acc[j];
    }
    bar_lds();  // (1) scp ready

    // D) all-wave redundant softmax; this lane: h=m, s-rows q*4..q*4+3.
    //    All waves compute identical values (same inputs, same instruction
    //    sequence); wave w writes Pt rows [4w,4w+4), wave0 writes alphaS.
    {
      float sc[4];
      const int* mks = (const int*)&mk;
#pragma unroll
      for (int j = 0; j < 4; ++j) {
        const int s = q * 4 + j;
        float vv = scp[0][s][m] + scp[1][s][m] + scp[2][s][m] + scp[3][s][m];
        if (mks[j] == 0) vv = -1e9f;  // match reference
        sc[j] = vv;
      }
      float tm = fmaxf(fmaxf(sc[0], sc[1]), fmaxf(sc[2], sc[3]));
      tm = fmaxf(tm, __shfl_xor(tm, 16));
      tm = fmaxf(tm, __shfl_xor(tm, 32));
      const float nm = fmaxf(m_reg, tm);
      const float al = __expf(m_reg - nm);
      const float p0 = __expf(sc[0] - nm), p1 = __expf(sc[1] - nm);
      const float p2 = __expf(sc[2] - nm), p3 = __expf(sc[3] - nm);
      if (q == w) {
        Pt[q * 4 + 0][m] = p0; Pt[q * 4 + 1][m] = p1;
        Pt[q * 4 + 2][m] = p2; Pt[q * 4 + 3][m] = p3;
      }
      float ps = (p0 + p1) + (p2 + p3);
      ps += __shfl_xor(ps, 16);
      ps += __shfl_xor(ps, 32);
      l_reg = l_reg * al + ps;
      m_reg = nm;
      if (t < 16) alphaS[t] = al;  // t<16 => w==0, q==0, h==t
    }
    // E) convert+write the prefetched tile into the other buffer (vmcnt waits
    //    happen here, after ~2 phases of latency cover)
    if (pf) {
#pragma unroll
      for (int i = 0; i < 16; ++i)
        *(uint2*)&xbuf[nxt][i][e0] =
            make_uint2(pk2(v[i].x, v[i].y), pk2(v[i].z, v[i].w));
      mk = mk_n;
    }
    bar_lds();  // (2) Pt/alphaS visible; xbuf[nxt] staged

    // G) accumulate: c[h][:] = c[h][:]*alpha[h] + sum_s P[s][h]*x[s][e0..e0+3]
    {
#pragma unroll
      for (int h = 0; h < 16; ++h) {
        const float a = alphaS[h];
        c[h][0] *= a; c[h][1] *= a; c[h][2] *= a; c[h][3] *= a;
      }
#pragma unroll
      for (int s = 0; s < 16; ++s) {
        union { uint2 uv; ushort_t u[4]; } xr;
        xr.uv = *(const uint2*)&xbuf[cur][s][e0];
        union { unsigned int i; float f; } cv;
        cv.i = (unsigned int)xr.u[0] << 16; const float x0 = cv.f;
        cv.i = (unsigned int)xr.u[1] << 16; const float x1 = cv.f;
        cv.i = (unsigned int)xr.u[2] << 16; const float x2 = cv.f;
        cv.i = (unsigned int)xr.u[3] << 16; const float x3 = cv.f;
        float p[16];
        *(float4*)&p[0]  = *(const float4*)&Pt[s][0];
        *(float4*)&p[4]  = *(const float4*)&Pt[s][4];
        *(float4*)&p[8]  = *(const float4*)&Pt[s][8];
        *(float4*)&p[12] = *(const float4*)&Pt[s][12];
#pragma unroll
        for (int h = 0; h < 16; ++h) {
          c[h][0] += p[h] * x0; c[h][1] += p[h] * x1;
          c[h][2] += p[h] * x2; c[h][3] += p[h] * x3;
        }
      }
    }
    // No third barrier: every conflicting write of iter it+1 (scp at B, Pt /
    // alphaS at D, xbuf[cur] at E) occurs after iter it+1's barrier (1), and
    // bar_lds retires this wave's LDS reads before it signals arrival there.
  }

  // write chunk partials: c (f32) and (m,l) per head
  const size_t base = ((size_t)b * NC + chunk) * H_ * E_;
#pragma unroll
  for (int h = 0; h < 16; ++h)
    *(float4*)&cpart[base + (size_t)h * E_ + e0] =
        make_float4(c[h][0], c[h][1], c[h][2], c[h][3]);
  if (t < 16) {  // w==0, q==0 lanes hold (m_reg,l_reg) for h = t
    mlpart[(((size_t)b * NC + chunk) * H_ + t) * 2 + 0] = m_reg;
    mlpart[(((size_t)b * NC + chunk) * H_ + t) * 2 + 1] = l_reg;
  }
}

// ---------------------------------------------------------------------------
// Kernel C: combine chunk partials for one (b,h), then out = (c/L)@Wv_h + bv_h
// ---------------------------------------------------------------------------
__global__ __launch_bounds__(256) void combine_kernel(
    const float* __restrict__ cpart, const float* __restrict__ mlpart,
    const float* __restrict__ Wv, const float* __restrict__ bvp,
    float* __restrict__ out, int NC) {
  __shared__ __align__(16) float wS[64];
  __shared__ __align__(16) float cnS[1024];
  __shared__ __align__(16) float vp[4][64];
  __shared__ float invLS;
  const int b = blockIdx.x / H_, h = blockIdx.x % H_;
  const int t = threadIdx.x;

  if (t < 64) {
    float m_i = -3e38f, l_i = 0.f;
    if (t < NC) {
      const size_t mi = (((size_t)b * NC + t) * H_ + h) * 2;
      m_i = mlpart[mi]; l_i = mlpart[mi + 1];
    }
    float M = m_i;
#pragma unroll
    for (int dlt = 1; dlt < 64; dlt <<= 1) M = fmaxf(M, __shfl_xor(M, dlt));
    const float wi = (t < NC) ? __expf(m_i - M) : 0.f;
    float Lp = l_i * wi;
#pragma unroll
    for (int dlt = 1; dlt < 64; dlt <<= 1) Lp += __shfl_xor(Lp, dlt);
    if (t < NC) wS[t] = wi;
    if (t == 0) invLS = 1.f / Lp;
  }
  __syncthreads();

  // combine c partials, normalize
  {
    const int e0 = t * 4;
    float a0 = 0.f, a1 = 0.f, a2 = 0.f, a3 = 0.f;
    for (int i = 0; i < NC; ++i) {
      const float wi = wS[i];
      const float4 v =
          *(const float4*)&cpart[(((size_t)b * NC + i) * H_ + h) * E_ + e0];
      a0 += wi * v.x; a1 += wi * v.y; a2 += wi * v.z; a3 += wi * v.w;
    }
    const float inv = invLS;
    *(float4*)&cnS[e0] = make_float4(a0 * inv, a1 * inv, a2 * inv, a3 * inv);
  }
  __syncthreads();

  // tiny GEMV: out_n = sum_e cn[e] * Wv[e, h*64+n]  (coalesced across n)
  {
    const int n = t & 63, part = t >> 6;
    const float* wv = Wv + h * NV_ + n;
    float sum = 0.f;
    const int eb = part * 256;
#pragma unroll 8
    for (int e = eb; e < eb + 256; ++e)
      sum += cnS[e] * wv[(size_t)e * E_];
    vp[part][n] = sum;
  }
  __syncthreads();
  if (t < 64) {
    const float o = vp[0][t] + vp[1][t] + vp[2][t] + vp[3][t] + bvp[h * NV_ + t];
    out[(size_t)b * E_ + h * NV_ + t] = o;
  }
}

// ---------------------------------------------------------------------------
extern "C" void kernel_launch(void* const* d_in, const int* in_sizes, int n_in,
                              void* d_out, int out_size, void* d_ws, size_t ws_size,
                              hipStream_t stream) {
  const float* seq1 = (const float*)d_in[0];
  const float* seq2 = (const float*)d_in[1];
  const int*   mask = (const int*)d_in[2];
  const float* Wq   = (const float*)d_in[3];
  const float* bq   = (const float*)d_in[4];
  const float* Wk   = (const float*)d_in[5];
  // d_in[6] = bk: softmax-invariant, skipped
  const float* Wv   = (const float*)d_in[7];
  const float* bv   = (const float*)d_in[8];
  float* out = (float*)d_out;

  // workspace: r_bf (1 MB bf16) | cpart (B*NC*H*E f32) | mlpart
  const size_t rbytes = (size_t)B_ * H_ * E_ * 2;
  int NC = 16;
  while (NC > 1) {
    const size_t need = rbytes + (size_t)B_ * NC * H_ * E_ * 4
                               + (size_t)B_ * NC * H_ * 2 * 4;
    if (need <= ws_size) break;
    NC >>= 1;
  }
  const int TPC = (S_ / NC) / 16;
  ushort_t* r_bf = (ushort_t*)d_ws;
  float* cpart   = (float*)((char*)d_ws + rbytes);
  float* mlpart  = (float*)((char*)d_ws + rbytes + (size_t)B_ * NC * H_ * E_ * 4);

  qr_kernel<<<dim3(B_ * H_), dim3(256), 0, stream>>>(seq1, Wq, bq, Wk, r_bf);
  attn_kernel<<<dim3(NC, B_), dim3(256), 0, stream>>>(seq2, mask, r_bf, cpart,
                                                      mlpart, NC, TPC);
  combine_kernel<<<dim3(B_ * H_), dim3(256), 0, stream>>>(cpart, mlpart, Wv, bv,
                                                          out, NC);
}

// Round 2
// 816.717 us; speedup vs baseline: 1.0481x; 1.0481x over previous
//
#include <hip/hip_runtime.h>

// Problem constants (MultiHeadAttention_79431125172249)
// All float tensors are fp32 (reference dtype); mask is int32; output fp32.
#define B_  32
#define S_  4096
#define E_  1024
#define H_  16
#define D_  64
#define NV_ 64
#define HD_ 1024   // H_*D_

typedef unsigned short ushort_t;
typedef __attribute__((ext_vector_type(8))) short  short8;   // 8 x bf16 (4 VGPRs)
typedef __attribute__((ext_vector_type(4))) float  floatx4;  // MFMA f32 acc
typedef __attribute__((ext_vector_type(4))) float  f32x4;    // for nontemporal ld

__device__ __forceinline__ ushort_t f2b(float f) {  // fp32 -> bf16 RNE
  union { float f; unsigned int u; } v; v.f = f;
  return (ushort_t)((v.u + 0x7FFFu + ((v.u >> 16) & 1u)) >> 16);
}
// pack two fp32 -> two bf16 (round-half-up; bias-free enough for 2% tol)
__device__ __forceinline__ unsigned int pk2(float lo, float hi) {
  union { float f; unsigned int u; } a, b; a.f = lo; b.f = hi;
  return ((a.u + 0x8000u) >> 16) | ((b.u + 0x8000u) & 0xFFFF0000u);
}

// ---------------------------------------------------------------------------
// Kernel A: q[b,h,:] = seq1[b]@Wq_h + bq_h  then  r[b,h,:] = (Wk_h @ q)/sqrt(D)
// r stored bf16 in workspace, layout [b][h][e]. bk skipped (softmax-invariant:
// it adds a per-(b,h) constant to every score in the row).
// ---------------------------------------------------------------------------
__global__ __launch_bounds__(256) void qr_kernel(
    const float* __restrict__ seq1, const float* __restrict__ Wq,
    const float* __restrict__ bq,   const float* __restrict__ Wk,
    ushort_t* __restrict__ r_bf) {
  __shared__ __align__(16) float qp[4][64];
  __shared__ __align__(16) float qv[64];
  const int b = blockIdx.x / H_, h = blockIdx.x % H_;
  const int t = threadIdx.x;
  const int d = t & 63, quarter = t >> 6;

  // stage 1: q_d = sum_e seq1[b,e] * Wq[e, h*64+d]; K=1024 split in 4 chunks
  {
    const float* s1 = seq1 + (size_t)b * E_;
    const float* wq = Wq + h * D_ + d;
    float sum = 0.f;
    const int e0 = quarter * 256;
#pragma unroll 8
    for (int e = e0; e < e0 + 256; ++e)
      sum += s1[e] * wq[(size_t)e * HD_];
    qp[quarter][d] = sum;
  }
  __syncthreads();
  if (t < 64) qv[t] = qp[0][t] + qp[1][t] + qp[2][t] + qp[3][t] + bq[h * D_ + t];
  __syncthreads();

  // stage 2: r_e = (1/8) * sum_d Wk[e, h*64+d] * q_d   (4 e's per thread)
  for (int i = 0; i < 4; ++i) {
    const int e = t + 256 * i;
    const float* wk = Wk + (size_t)e * HD_ + h * D_;
    float rs = 0.f;
#pragma unroll
    for (int g = 0; g < 16; ++g) {
      const float4 w4 = *(const float4*)(wk + g * 4);
      rs += w4.x * qv[g * 4 + 0] + w4.y * qv[g * 4 + 1] +
            w4.z * qv[g * 4 + 2] + w4.w * qv[g * 4 + 3];
    }
    r_bf[((size_t)b * H_ + h) * E_ + e] = f2b(rs * 0.125f);  // fold 1/sqrt(64)
  }
}

// ---------------------------------------------------------------------------
// Kernel B: flash pass over seq2. One block = (batch b, S-chunk). All 16 heads
// together. Per 16-row tile: stage fp32 X tile -> bf16 LDS, MFMA scores
// (16s x 16h, K=1024 over 4 waves), wave0 masked online-softmax, then all
// threads do the weighted row-sum c[h][e] outer-product (16h x 4e / thread).
// NOTE (R1 post-mortem): the double-buffered/prefetch restructure regressed
// ~60us (prefetch regs spilled under launch_bounds cap); 2-blocks/CU TLP
// already overlaps stage & compute here — this serial-phase form is within
// ~10% of the seq2 HBM floor. seq2 loads are nontemporal (zero reuse).
// ---------------------------------------------------------------------------
__global__ __launch_bounds__(256) void attn_kernel(
    const float* __restrict__ seq2, const int* __restrict__ mask,
    const ushort_t* __restrict__ r_bf, float* __restrict__ cpart,
    float* __restrict__ mlpart, int NC, int TPC) {
  __shared__ __align__(16) ushort_t rS[16][1032];   // r rows per head (+pad)
  __shared__ __align__(16) ushort_t xS[16][1032];   // X tile rows, bf16
  __shared__ __align__(16) float scp[4][16][17];    // per-wave score partials
  __shared__ __align__(16) float Pt[16][16];        // p[s][h]
  __shared__ __align__(16) float mS[16], lS[16], alphaS[16];

  const int b = blockIdx.y, chunk = blockIdx.x;
  const int t = threadIdx.x;
  const int lane = t & 63, w = t >> 6;
  const int s0 = chunk * (TPC * 16);
  const int e0 = t * 4;                  // this thread's 4 e-columns

  // stage r for all 16 heads (16 x 1024 bf16)
  {
    const uint4* src = (const uint4*)(r_bf + (size_t)b * H_ * E_);
#pragma unroll
    for (int i = 0; i < 8; ++i) {
      const int f = t + 256 * i;
      *(uint4*)&rS[f >> 7][(f & 127) * 8] = src[f];
    }
  }
  if (t < 16) { mS[t] = -3e38f; lS[t] = 0.f; }

  float c[16][4];
#pragma unroll
  for (int h = 0; h < 16; ++h)
#pragma unroll
    for (int j = 0; j < 4; ++j) c[h][j] = 0.f;

  for (int it = 0; it < TPC; ++it) {
    const int st = s0 + it * 16;
    __syncthreads();  // protects xS/Pt readers of previous iteration
    // stage X tile: 16 rows x 1024 fp32 -> bf16 LDS, coalesced float4 loads.
    // seq2 is streamed exactly once -> nontemporal (keep L2 for r/cpart/mask).
    {
      const f32x4* src = (const f32x4*)(seq2 + ((size_t)b * S_ + st) * E_);
#pragma unroll
      for (int i = 0; i < 16; ++i) {
        const int f = t + 256 * i;          // [0,4096) float4 index
        const f32x4 v = __builtin_nontemporal_load(&src[f]);
        *(uint2*)&xS[f >> 8][(f & 255) * 4] =
            make_uint2(pk2(v.x, v.y), pk2(v.z, v.w));
      }
    }
    __syncthreads();

    // MFMA scores: wave w covers e in [w*256, w*256+256) -> 8 mfma k-steps
    {
      const int m = lane & 15, q = lane >> 4;
      floatx4 acc = {0.f, 0.f, 0.f, 0.f};
#pragma unroll
      for (int kk = 0; kk < 8; ++kk) {
        const int kb = w * 256 + kk * 32 + q * 8;
        short8 av  = *(const short8*)&xS[m][kb];  // A[m=s][k=e]
        short8 bvf = *(const short8*)&rS[m][kb];  // B[n=h][k=e] (K-major)
        acc = __builtin_amdgcn_mfma_f32_16x16x32_bf16(av, bvf, acc, 0, 0, 0);
      }
#pragma unroll
      for (int j = 0; j < 4; ++j)
        scp[w][q * 4 + j][m] = acc[j];  // C: col=lane&15 (=n=h), row=q*4+j (=s)
    }
    __syncthreads();

    // wave 0: reduce 4 K-partials, mask, online softmax, write P
    if (w == 0) {
      const int h = lane & 15, sg = lane >> 4;
      float sc[4];
#pragma unroll
      for (int j = 0; j < 4; ++j) {
        const int s = sg * 4 + j;
        float v = scp[0][s][h] + scp[1][s][h] + scp[2][s][h] + scp[3][s][h];
        if (mask[(size_t)b * S_ + st + s] == 0) v = -1e9f;  // match reference
        sc[j] = v;
      }
      float tm = fmaxf(fmaxf(sc[0], sc[1]), fmaxf(sc[2], sc[3]));
      tm = fmaxf(tm, __shfl_xor(tm, 16));
      tm = fmaxf(tm, __shfl_xor(tm, 32));
      const float mo = mS[h];
      const float nm = fmaxf(mo, tm);
      const float al = __expf(mo - nm);
      float ps = 0.f;
#pragma unroll
      for (int j = 0; j < 4; ++j) {
        const float p = __expf(sc[j] - nm);
        Pt[sg * 4 + j][h] = p;
        ps += p;
      }
      ps += __shfl_xor(ps, 16);
      ps += __shfl_xor(ps, 32);
      if (lane < 16) { mS[h] = nm; alphaS[h] = al; lS[h] = lS[h] * al + ps; }
    }
    __syncthreads();

    // accumulate: c[h][:] = c[h][:]*alpha[h] + sum_s P[s][h] * x[s][e0..e0+3]
    {
#pragma unroll
      for (int h = 0; h < 16; ++h) {
        const float a = alphaS[h];
        c[h][0] *= a; c[h][1] *= a; c[h][2] *= a; c[h][3] *= a;
      }
#pragma unroll
      for (int s = 0; s < 16; ++s) {
        union { uint2 v; ushort_t u[4]; } xr;
        xr.v = *(const uint2*)&xS[s][e0];
        union { unsigned int i; float f; } cv;
        cv.i = (unsigned int)xr.u[0] << 16; const float x0 = cv.f;
        cv.i = (unsigned int)xr.u[1] << 16; const float x1 = cv.f;
        cv.i = (unsigned int)xr.u[2] << 16; const float x2 = cv.f;
        cv.i = (unsigned int)xr.u[3] << 16; const float x3 = cv.f;
        float p[16];
        *(float4*)&p[0]  = *(const float4*)&Pt[s][0];
        *(float4*)&p[4]  = *(const float4*)&Pt[s][4];
        *(float4*)&p[8]  = *(const float4*)&Pt[s][8];
        *(float4*)&p[12] = *(const float4*)&Pt[s][12];
#pragma unroll
        for (int h = 0; h < 16; ++h) {
          c[h][0] += p[h] * x0; c[h][1] += p[h] * x1;
          c[h][2] += p[h] * x2; c[h][3] += p[h] * x3;
        }
      }
    }
  }

  // write chunk partials: c (f32) and (m,l) per head
  const size_t base = ((size_t)b * NC + chunk) * H_ * E_;
#pragma unroll
  for (int h = 0; h < 16; ++h)
    *(float4*)&cpart[base + (size_t)h * E_ + e0] =
        make_float4(c[h][0], c[h][1], c[h][2], c[h][3]);
  if (t < 16) {  // wave0 lanes that wrote mS/lS themselves (no race)
    mlpart[(((size_t)b * NC + chunk) * H_ + t) * 2 + 0] = mS[t];
    mlpart[(((size_t)b * NC + chunk) * H_ + t) * 2 + 1] = lS[t];
  }
}

// ---------------------------------------------------------------------------
// Kernel C: combine chunk partials for one (b,h), then out = (c/L)@Wv_h + bv_h
// ---------------------------------------------------------------------------
__global__ __launch_bounds__(256) void combine_kernel(
    const float* __restrict__ cpart, const float* __restrict__ mlpart,
    const float* __restrict__ Wv, const float* __restrict__ bvp,
    float* __restrict__ out, int NC) {
  __shared__ __align__(16) float wS[64];
  __shared__ __align__(16) float cnS[1024];
  __shared__ __align__(16) float vp[4][64];
  __shared__ float invLS;
  const int b = blockIdx.x / H_, h = blockIdx.x % H_;
  const int t = threadIdx.x;

  if (t < 64) {
    float m_i = -3e38f, l_i = 0.f;
    if (t < NC) {
      const size_t mi = (((size_t)b * NC + t) * H_ + h) * 2;
      m_i = mlpart[mi]; l_i = mlpart[mi + 1];
    }
    float M = m_i;
#pragma unroll
    for (int dlt = 1; dlt < 64; dlt <<= 1) M = fmaxf(M, __shfl_xor(M, dlt));
    const float wi = (t < NC) ? __expf(m_i - M) : 0.f;
    float Lp = l_i * wi;
#pragma unroll
    for (int dlt = 1; dlt < 64; dlt <<= 1) Lp += __shfl_xor(Lp, dlt);
    if (t < NC) wS[t] = wi;
    if (t == 0) invLS = 1.f / Lp;
  }
  __syncthreads();

  // combine c partials, normalize
  {
    const int e0 = t * 4;
    float a0 = 0.f, a1 = 0.f, a2 = 0.f, a3 = 0.f;
    for (int i = 0; i < NC; ++i) {
      const float wi = wS[i];
      const float4 v =
          *(const float4*)&cpart[(((size_t)b * NC + i) * H_ + h) * E_ + e0];
      a0 += wi * v.x; a1 += wi * v.y; a2 += wi * v.z; a3 += wi * v.w;
    }
    const float inv = invLS;
    *(float4*)&cnS[e0] = make_float4(a0 * inv, a1 * inv, a2 * inv, a3 * inv);
  }
  __syncthreads();

  // tiny GEMV: out_n = sum_e cn[e] * Wv[e, h*64+n]  (coalesced across n)
  {
    const int n = t & 63, part = t >> 6;
    const float* wv = Wv + h * NV_ + n;
    float sum = 0.f;
    const int eb = part * 256;
#pragma unroll 8
    for (int e = eb; e < eb + 256; ++e)
      sum += cnS[e] * wv[(size_t)e * E_];
    vp[part][n] = sum;
  }
  __syncthreads();
  if (t < 64) {
    const float o = vp[0][t] + vp[1][t] + vp[2][t] + vp[3][t] + bvp[h * NV_ + t];
    out[(size_t)b * E_ + h * NV_ + t] = o;
  }
}

// ---------------------------------------------------------------------------
extern "C" void kernel_launch(void* const* d_in, const int* in_sizes, int n_in,
                              void* d_out, int out_size, void* d_ws, size_t ws_size,
                              hipStream_t stream) {
  const float* seq1 = (const float*)d_in[0];
  const float* seq2 = (const float*)d_in[1];
  const int*   mask = (const int*)d_in[2];
  const float* Wq   = (const float*)d_in[3];
  const float* bq   = (const float*)d_in[4];
  const float* Wk   = (const float*)d_in[5];
  // d_in[6] = bk: softmax-invariant, skipped
  const float* Wv   = (const float*)d_in[7];
  const float* bv   = (const float*)d_in[8];
  float* out = (float*)d_out;

  // workspace: r_bf (1 MB bf16) | cpart (B*NC*H*E f32) | mlpart
  const size_t rbytes = (size_t)B_ * H_ * E_ * 2;
  int NC = 16;
  while (NC > 1) {
    const size_t need = rbytes + (size_t)B_ * NC * H_ * E_ * 4
                               + (size_t)B_ * NC * H_ * 2 * 4;
    if (need <= ws_size) break;
    NC >>= 1;
  }
  const int TPC = (S_ / NC) / 16;
  ushort_t* r_bf = (ushort_t*)d_ws;
  float* cpart   = (float*)((char*)d_ws + rbytes);
  float* mlpart  = (float*)((char*)d_ws + rbytes + (size_t)B_ * NC * H_ * E_ * 4);

  qr_kernel<<<dim3(B_ * H_), dim3(256), 0, stream>>>(seq1, Wq, bq, Wk, r_bf);
  attn_kernel<<<dim3(NC, B_), dim3(256), 0, stream>>>(seq2, mask, r_bf, cpart,
                                                      mlpart, NC, TPC);
  combine_kernel<<<dim3(B_ * H_), dim3(256), 0, stream>>>(cpart, mlpart, Wv, bv,
                                                          out, NC);
}